// Round 15
// baseline (63.853 us; speedup 1.0000x reference)
//
#include <hip/hip_runtime.h>
#include <math.h>

#define A_N      5
#define GRID_HW  52
#define NCLS     80
#define CH       85
#define SCORE_T  0.15f
#define IOU_T    0.5f
#define NEGV     (-1e9f)
#define MAXOUT   10

#define WAVES_PB     4                  // waves per decode block
#define BPW          32                 // boxes per wave
#define WAVE_FLOATS  (BPW * CH)         // 2720 floats = 10,880 B per wave
#define WAVE_FULL    10                 // 10 x 64 lanes x 16 B = 640 float4
#define WAVE_TAIL    40                 // +40 float4 = 680 = 2720 floats

#define NMS_THREADS  512                // 8 waves
#define NWAVES       (NMS_THREADS / 64)
#define NMS_BLOCKS   256                // redundant blocks: keep all CUs busy
#define NCAP         4096               // register fast-path capacity
#define KR           (NCAP / NMS_THREADS)   // 8 register slots per thread

// fast exp: v_exp_f32 (~1e-7 rel err). Argmax uses raw logits (exact); score
// values have 1.54 tolerance; proven across rounds 4-14 (absmax 0).
__device__ __forceinline__ float fexp(float x) { return __expf(x); }

// async global->LDS, 16B/lane. LDS dest = wave-uniform base + lane*16.
__device__ __forceinline__ void gload_lds16(const float* g, float* l) {
    __builtin_amdgcn_global_load_lds(
        (const __attribute__((address_space(1))) unsigned int*)g,
        (__attribute__((address_space(3))) unsigned int*)l, 16, 0, 0);
}

__global__ void init_counter_kernel(int* __restrict__ counter) {
    *counter = 0;
}

// ---------------------------------------------------------------------------
// Decode (unchanged): 4 independent waves/block, each stages its own 32-box
// segment via global_load_lds, wave-local vmcnt drain, 2 lanes/box one-pass
// softmax, ballot-compacted output (1 atomic/wave).
// ---------------------------------------------------------------------------
__global__ __launch_bounds__(256) void decode_kernel(
    const float* __restrict__ preds,
    const float* __restrict__ anchors,
    float4* __restrict__ pbox, float* __restrict__ pscore,
    float* __restrict__ pcls,
    int* __restrict__ counter, int N, int capacity)
{
    __shared__ __align__(16) float lds[WAVES_PB * WAVE_FLOATS];

    const int lane = (int)threadIdx.x & 63;
    const int wid  = (int)threadIdx.x >> 6;
    const int wt   = blockIdx.x * WAVES_PB + wid;   // wave-tile (32 boxes)
    if (wt * BPW >= N) return;                      // whole-wave guard

    const float* gbase = preds + (size_t)wt * WAVE_FLOATS;
    float* lbase = lds + wid * WAVE_FLOATS;

#pragma unroll
    for (int i = 0; i < WAVE_FULL; ++i)
        gload_lds16(gbase + (size_t)(i * 64 + lane) * 4, lbase + i * 256);
    if (lane < WAVE_TAIL)
        gload_lds16(gbase + (size_t)(WAVE_FULL * 64 + lane) * 4,
                    lbase + WAVE_FULL * 256);

    asm volatile("s_waitcnt vmcnt(0)" ::: "memory");
    __builtin_amdgcn_sched_barrier(0);

    const int b  = lane >> 1;            // box within wave segment (0..31)
    const int h  = lane & 1;             // half of the 80 classes
    const int gi = wt * BPW + b;
    const float* bp = lbase + b * CH;
    const float* cl = bp + 5 + h * 40;

    float s = 0.0f;
    float m = -INFINITY;
    int   am = h * 40;
#pragma unroll
    for (int j = 0; j < 40; ++j) {
        float x = cl[j];
        s += fexp(x);
        if (x > m) { m = x; am = h * 40 + j; }
    }
    {
        float m2 = __shfl_xor(m, 1);
        float s2 = __shfl_xor(s, 1);
        int   am2 = __shfl_xor(am, 1);
        s += s2;
        if (m2 > m || (m2 == m && am2 < am)) { m = m2; am = am2; }
    }

    float conf  = 1.0f / (1.0f + fexp(-bp[4]));
    float score = conf * fexp(m) / s;

    bool live = (h == 0) && (gi < N) && (score >= SCORE_T);

    unsigned long long mask = __ballot(live);
    if (mask) {
        int nlive  = __popcll(mask);
        int leader = (int)__ffsll((long long)mask) - 1;
        int base_ = 0;
        if (lane == leader) base_ = atomicAdd(counter, nlive);
        base_ = __shfl(base_, leader);
        if (live) {
            int a = gi % A_N;
            int t = gi / A_N;
            int wx = t % GRID_HW;
            int hy = (t / GRID_HW) % GRID_HW;
            const float inv = 1.0f / (float)GRID_HW;
            float cx = (1.0f / (1.0f + fexp(-bp[0])) + (float)wx) * inv;
            float cy = (1.0f / (1.0f + fexp(-bp[1])) + (float)hy) * inv;
            float bw = fexp(bp[2]) * anchors[2 * a]     * inv;
            float bh = fexp(bp[3]) * anchors[2 * a + 1] * inv;

            int pos = base_ + __popcll(mask & ((1ull << lane) - 1));
            if (pos < capacity) {
                pbox[pos]   = make_float4(cy - 0.5f * bh, cx - 0.5f * bw,
                                          cy + 0.5f * bh, cx + 0.5f * bw);
                pscore[pos] = score;
                pcls[pos]   = (float)am;
            }
        }
    }
}

// ---------------------------------------------------------------------------
// NMS, clock-theory test: NMS_BLOCKS=256 blocks all run the IDENTICAL
// register-resident fast path (read-only inputs, private registers/LDS);
// only block 0 writes the output. Per-block work is unchanged vs round 14 —
// if the ~30us floor was DVFS (1 busy CU -> min SCLK), 256 busy CUs hold the
// high clock state and this dispatch collapses to the ~5us the cycle model
// predicts. Fallback (M > NCAP, never hit: M~1500) runs on block 0 only.
// ---------------------------------------------------------------------------
__global__ __launch_bounds__(NMS_THREADS, 1) void nms_kernel(
    const float4* __restrict__ pbox, float* __restrict__ pscore,
    const float* __restrict__ pcls, const int* __restrict__ counter,
    int capacity, float* __restrict__ pscratch, float* __restrict__ out)
{
    __shared__ float psc[NWAVES];
    __shared__ int   pix[NWAVES];
    __shared__ float orow[MAXOUT * 6];

    int M = *counter;
    if (M > capacity) M = capacity;
    const int tid  = (int)threadIdx.x;
    const int lane = tid & 63;
    const int wid  = tid >> 6;

    if (M <= NCAP) {
        // -------- fast path: everything in registers; all blocks redundant --
        float4 rb[KR];
        float  rs[KR];
#pragma unroll
        for (int k = 0; k < KR; ++k) {
            int j = tid + (k << 9);                 // k * 512
            if (j < M) { rb[k] = pbox[j]; rs[k] = pscore[j]; }
            else       { rs[k] = -INFINITY; rb[k] = make_float4(0.f,0.f,0.f,0.f); }
        }

        for (int it = 0; it < MAXOUT; ++it) {
            float bs = -INFINITY; int bi = -1;
#pragma unroll
            for (int k = 0; k < KR; ++k) {          // ascending j => first-max
                if (rs[k] > bs) { bs = rs[k]; bi = tid + (k << 9); }
            }
#pragma unroll
            for (int off = 32; off; off >>= 1) {    // score desc, idx asc
                float os = __shfl_xor(bs, off);
                int   oi = __shfl_xor(bi, off);
                if (os > bs || (os == bs && oi != -1 && (bi == -1 || oi < bi))) {
                    bs = os; bi = oi;
                }
            }
            if (lane == 0) { psc[wid] = bs; pix[wid] = bi; }
            __syncthreads();

            bs = psc[0]; bi = pix[0];
#pragma unroll
            for (int w = 1; w < NWAVES; ++w) {
                float os = psc[w]; int oi = pix[w];
                if (os > bs || (os == bs && oi != -1 && (bi == -1 || oi < bi))) {
                    bs = os; bi = oi;
                }
            }
            bool valid = (bi >= 0) && (bs > NEGV * 0.5f);

            float4 wb = make_float4(0.f, 0.f, 0.f, 0.f);
            if (valid) wb = pbox[bi];               // uniform broadcast, cached

            if (tid == 0) {
                if (valid) {
                    orow[it*6+0] = wb.x; orow[it*6+1] = wb.y;
                    orow[it*6+2] = wb.z; orow[it*6+3] = wb.w;
                    orow[it*6+4] = bs;   orow[it*6+5] = pcls[bi];
                } else {
                    orow[it*6+0] = 0.f; orow[it*6+1] = 0.f; orow[it*6+2] = 0.f;
                    orow[it*6+3] = 0.f; orow[it*6+4] = 0.f; orow[it*6+5] = 0.f;
                }
            }

            if (valid) {
                float a1 = fmaxf(wb.z - wb.x, 0.f) * fmaxf(wb.w - wb.y, 0.f);
#pragma unroll
                for (int k = 0; k < KR; ++k) {      // pure register math
                    int j = tid + (k << 9);
                    if (j == bi) rs[k] = NEGV;      // reference kills selected
                    float ty = fmaxf(wb.x, rb[k].x);
                    float tx = fmaxf(wb.y, rb[k].y);
                    float by = fminf(wb.z, rb[k].z);
                    float bx = fminf(wb.w, rb[k].w);
                    float inter = fmaxf(by - ty, 0.f) * fmaxf(bx - tx, 0.f);
                    float a2 = fmaxf(rb[k].z - rb[k].x, 0.f)
                             * fmaxf(rb[k].w - rb[k].y, 0.f);
                    float iou = inter / (a1 + a2 - inter + 1e-9f);
                    if (iou > IOU_T) rs[k] = NEGV;
                }
            }
            __syncthreads();   // protect psc/pix for next iteration
        }

        __syncthreads();
        if (blockIdx.x == 0 && tid < MAXOUT * 6)
            out[tid] = orow[tid];                   // block 0 writes output
    } else {
        // -------- fallback: block 0 only, idempotent via pscratch ----------
        if (blockIdx.x != 0) return;
        for (int j = tid; j < M; j += NMS_THREADS) pscratch[j] = pscore[j];
        __syncthreads();

        for (int it = 0; it < MAXOUT; ++it) {
            float bs = -INFINITY; int bi = -1;
            for (int j = tid; j < M; j += NMS_THREADS) {
                float v = pscratch[j];
                if (v > bs) { bs = v; bi = j; }
            }
#pragma unroll
            for (int off = 32; off; off >>= 1) {
                float os = __shfl_xor(bs, off);
                int   oi = __shfl_xor(bi, off);
                if (os > bs || (os == bs && oi != -1 && (bi == -1 || oi < bi))) {
                    bs = os; bi = oi;
                }
            }
            if (lane == 0) { psc[wid] = bs; pix[wid] = bi; }
            __syncthreads();
            bs = psc[0]; bi = pix[0];
#pragma unroll
            for (int w = 1; w < NWAVES; ++w) {
                float os = psc[w]; int oi = pix[w];
                if (os > bs || (os == bs && oi != -1 && (bi == -1 || oi < bi))) {
                    bs = os; bi = oi;
                }
            }
            bool valid = (bi >= 0) && (bs > NEGV * 0.5f);
            float4 wb = make_float4(0.f, 0.f, 0.f, 0.f);
            if (valid) wb = pbox[bi];
            if (tid == 0) {
                if (valid) {
                    orow[it*6+0] = wb.x; orow[it*6+1] = wb.y;
                    orow[it*6+2] = wb.z; orow[it*6+3] = wb.w;
                    orow[it*6+4] = bs;   orow[it*6+5] = pcls[bi];
                    pscratch[bi] = NEGV;
                } else {
                    orow[it*6+0] = 0.f; orow[it*6+1] = 0.f; orow[it*6+2] = 0.f;
                    orow[it*6+3] = 0.f; orow[it*6+4] = 0.f; orow[it*6+5] = 0.f;
                }
            }
            __syncthreads();
            if (valid) {
                float a1 = fmaxf(wb.z - wb.x, 0.f) * fmaxf(wb.w - wb.y, 0.f);
                for (int j = tid; j < M; j += NMS_THREADS) {
                    float4 bj = pbox[j];
                    float ty = fmaxf(wb.x, bj.x);
                    float tx = fmaxf(wb.y, bj.y);
                    float by = fminf(wb.z, bj.z);
                    float bx = fminf(wb.w, bj.w);
                    float inter = fmaxf(by - ty, 0.f) * fmaxf(bx - tx, 0.f);
                    float a2 = fmaxf(bj.z - bj.x, 0.f) * fmaxf(bj.w - bj.y, 0.f);
                    float iou = inter / (a1 + a2 - inter + 1e-9f);
                    if (iou > IOU_T) pscratch[j] = NEGV;
                }
            }
            __syncthreads();
        }

        __syncthreads();
        if (tid < MAXOUT * 6) out[tid] = orow[tid];
    }
}

extern "C" void kernel_launch(void* const* d_in, const int* in_sizes, int n_in,
                              void* d_out, int out_size, void* d_ws, size_t ws_size,
                              hipStream_t stream) {
    (void)n_in; (void)out_size;
    const float* preds   = (const float*)d_in[0];
    const float* anchors = (const float*)d_in[1];
    float* out = (float*)d_out;

    int N = in_sizes[0] / CH;   // 216,320 boxes

    // Workspace: [0,64) counter; pbox float4[cap]; pscore, pcls, pscratch.
    char* ws = (char*)d_ws;
    int* counter = (int*)ws;
    size_t avail = (ws_size > 64) ? (ws_size - 64) : 0;
    long long cap = (long long)(avail / (sizeof(float4) + 3 * sizeof(float)));
    if (cap > N) cap = N;
    if (cap < 0) cap = 0;
    int capacity = (int)cap;

    float4* pbox    = (float4*)(ws + 64);
    float* pscore   = (float*)(pbox + capacity);
    float* pcls     = pscore + capacity;
    float* pscratch = pcls + capacity;

    init_counter_kernel<<<1, 1, 0, stream>>>(counter);

    int nBlocks = (N + WAVES_PB * BPW - 1) / (WAVES_PB * BPW);   // 1690
    decode_kernel<<<nBlocks, 256, 0, stream>>>(
        preds, anchors, pbox, pscore, pcls, counter, N, capacity);
    nms_kernel<<<NMS_BLOCKS, NMS_THREADS, 0, stream>>>(
        pbox, pscore, pcls, counter, capacity, pscratch, out);
}

// Round 16
// 62.211 us; speedup vs baseline: 1.0264x; 1.0264x over previous
//
#include <hip/hip_runtime.h>
#include <math.h>

#define A_N      5
#define GRID_HW  52
#define NCLS     80
#define CH       85
#define SCORE_T  0.15f
#define IOU_T    0.5f
#define NEGV     (-1e9f)
#define MAXOUT   10

#define WAVES_PB     4                  // waves per decode block
#define BPW          32                 // boxes per wave
#define WAVE_FLOATS  (BPW * CH)         // 2720 floats = 10,880 B per wave
#define WAVE_FULL    10                 // 10 x 64 lanes x 16 B = 640 float4
#define WAVE_TAIL    40                 // +40 float4 = 680 = 2720 floats

#define NMS_THREADS  512                // 8 waves
#define NWAVES       (NMS_THREADS / 64)
#define NCAP         4096               // fast-path capacity (M ~1500 measured)
#define KR           (NCAP / NMS_THREADS)   // 8 register slots per thread

// fast exp: v_exp_f32 (~1e-7 rel err). Argmax uses raw logits (exact); score
// values have 1.54 tolerance; proven across rounds 4-15 (absmax 0).
__device__ __forceinline__ float fexp(float x) { return __expf(x); }

// async global->LDS, 16B/lane. LDS dest = wave-uniform base + lane*16.
__device__ __forceinline__ void gload_lds16(const float* g, float* l) {
    __builtin_amdgcn_global_load_lds(
        (const __attribute__((address_space(1))) unsigned int*)g,
        (__attribute__((address_space(3))) unsigned int*)l, 16, 0, 0);
}

__global__ void init_counter_kernel(int* __restrict__ counter) {
    *counter = 0;
}

// ---------------------------------------------------------------------------
// Decode (unchanged): 4 independent waves/block, each stages its own 32-box
// segment via global_load_lds, wave-local vmcnt drain, 2 lanes/box one-pass
// softmax, ballot-compacted output (1 atomic/wave).
// ---------------------------------------------------------------------------
__global__ __launch_bounds__(256) void decode_kernel(
    const float* __restrict__ preds,
    const float* __restrict__ anchors,
    float4* __restrict__ pbox, float* __restrict__ pscore,
    float* __restrict__ pcls,
    int* __restrict__ counter, int N, int capacity)
{
    __shared__ __align__(16) float lds[WAVES_PB * WAVE_FLOATS];

    const int lane = (int)threadIdx.x & 63;
    const int wid  = (int)threadIdx.x >> 6;
    const int wt   = blockIdx.x * WAVES_PB + wid;   // wave-tile (32 boxes)
    if (wt * BPW >= N) return;                      // whole-wave guard

    const float* gbase = preds + (size_t)wt * WAVE_FLOATS;
    float* lbase = lds + wid * WAVE_FLOATS;

#pragma unroll
    for (int i = 0; i < WAVE_FULL; ++i)
        gload_lds16(gbase + (size_t)(i * 64 + lane) * 4, lbase + i * 256);
    if (lane < WAVE_TAIL)
        gload_lds16(gbase + (size_t)(WAVE_FULL * 64 + lane) * 4,
                    lbase + WAVE_FULL * 256);

    asm volatile("s_waitcnt vmcnt(0)" ::: "memory");
    __builtin_amdgcn_sched_barrier(0);

    const int b  = lane >> 1;            // box within wave segment (0..31)
    const int h  = lane & 1;             // half of the 80 classes
    const int gi = wt * BPW + b;
    const float* bp = lbase + b * CH;
    const float* cl = bp + 5 + h * 40;

    float s = 0.0f;
    float m = -INFINITY;
    int   am = h * 40;
#pragma unroll
    for (int j = 0; j < 40; ++j) {
        float x = cl[j];
        s += fexp(x);
        if (x > m) { m = x; am = h * 40 + j; }
    }
    {
        float m2 = __shfl_xor(m, 1);
        float s2 = __shfl_xor(s, 1);
        int   am2 = __shfl_xor(am, 1);
        s += s2;
        if (m2 > m || (m2 == m && am2 < am)) { m = m2; am = am2; }
    }

    float conf  = 1.0f / (1.0f + fexp(-bp[4]));
    float score = conf * fexp(m) / s;

    bool live = (h == 0) && (gi < N) && (score >= SCORE_T);

    unsigned long long mask = __ballot(live);
    if (mask) {
        int nlive  = __popcll(mask);
        int leader = (int)__ffsll((long long)mask) - 1;
        int base_ = 0;
        if (lane == leader) base_ = atomicAdd(counter, nlive);
        base_ = __shfl(base_, leader);
        if (live) {
            int a = gi % A_N;
            int t = gi / A_N;
            int wx = t % GRID_HW;
            int hy = (t / GRID_HW) % GRID_HW;
            const float inv = 1.0f / (float)GRID_HW;
            float cx = (1.0f / (1.0f + fexp(-bp[0])) + (float)wx) * inv;
            float cy = (1.0f / (1.0f + fexp(-bp[1])) + (float)hy) * inv;
            float bw = fexp(bp[2]) * anchors[2 * a]     * inv;
            float bh = fexp(bp[3]) * anchors[2 * a + 1] * inv;

            int pos = base_ + __popcll(mask & ((1ull << lane) - 1));
            if (pos < capacity) {
                pbox[pos]   = make_float4(cy - 0.5f * bh, cx - 0.5f * bw,
                                          cy + 0.5f * bh, cx + 0.5f * bw);
                pscore[pos] = score;
                pcls[pos]   = (float)am;
            }
        }
    }
}

// ---------------------------------------------------------------------------
// NMS: one block, 512 threads (8 waves). Fast path (M <= 4096): scores+boxes
// in registers (KR=8, no spill); boxes+class ALSO staged once into LDS SoA.
// Per iteration the critical path is minimal:
//   reg scan -> 6-shfl butterfly -> psc/pix -> barrier A ->
//   WAVE 0 ONLY: combine 8 partials (16 broadcast reads) + winner lookup
//   (4 uniform LDS reads) + publish 5 LDS words -> barrier B ->
//   all waves: read winner (5 uniform reads) + REGISTER IoU suppression.
// No global loads/stores inside the loop; no 128+-read combines (the two
// elements that made rounds 11/14 ~3000 cyc/iter).
// ---------------------------------------------------------------------------
__global__ __launch_bounds__(NMS_THREADS, 1) void nms_kernel(
    const float4* __restrict__ pbox, float* __restrict__ pscore,
    const float* __restrict__ pcls, const int* __restrict__ counter,
    int capacity, float* __restrict__ pscratch, float* __restrict__ out)
{
    __shared__ float sy0[NCAP], sx0[NCAP], sy1[NCAP], sx1[NCAP], scl[NCAP];
    __shared__ float psc[NWAVES];
    __shared__ int   pix[NWAVES];
    __shared__ float wtup[4];           // winner box (y0,x0,y1,x1)
    __shared__ int   wbi;               // winner index (-1 = none)
    __shared__ float orow[MAXOUT * 6];

    int M = *counter;
    if (M > capacity) M = capacity;
    const int tid  = (int)threadIdx.x;
    const int lane = tid & 63;
    const int wid  = tid >> 6;

    if (M <= NCAP) {
        // -------- stage: registers (scan/suppress) + LDS SoA (winner) ------
        float4 rb[KR];
        float  rs[KR];
#pragma unroll
        for (int k = 0; k < KR; ++k) {
            int j = tid + (k << 9);                 // k * 512
            if (j < M) {
                float4 b = pbox[j];
                rb[k] = b; rs[k] = pscore[j];
                sy0[j] = b.x; sx0[j] = b.y; sy1[j] = b.z; sx1[j] = b.w;
                scl[j] = pcls[j];
            } else {
                rs[k] = -INFINITY;
                rb[k] = make_float4(0.f, 0.f, 0.f, 0.f);
            }
        }
        __syncthreads();

        for (int it = 0; it < MAXOUT; ++it) {
            // per-thread register argmax (ascending j => first-max)
            float bs = -INFINITY; int bi = -1;
#pragma unroll
            for (int k = 0; k < KR; ++k) {
                if (rs[k] > bs) { bs = rs[k]; bi = tid + (k << 9); }
            }
            // per-wave butterfly: score desc, index asc tie-break
#pragma unroll
            for (int off = 32; off; off >>= 1) {
                float os = __shfl_xor(bs, off);
                int   oi = __shfl_xor(bi, off);
                if (os > bs || (os == bs && oi != -1 && (bi == -1 || oi < bi))) {
                    bs = os; bi = oi;
                }
            }
            if (lane == 0) { psc[wid] = bs; pix[wid] = bi; }
            __syncthreads();                        // A: partials ready

            if (wid == 0) {
                // all 64 lanes of wave 0 combine redundantly (broadcast reads)
                float cbs = psc[0]; int cbi = pix[0];
#pragma unroll
                for (int w = 1; w < NWAVES; ++w) {
                    float os = psc[w]; int oi = pix[w];
                    if (os > cbs || (os == cbs && oi != -1 && (cbi == -1 || oi < cbi))) {
                        cbs = os; cbi = oi;
                    }
                }
                bool valid = (cbi >= 0) && (cbs > NEGV * 0.5f);
                if (lane == 0) {
                    wbi = valid ? cbi : -1;
                    if (valid) {
                        float y0 = sy0[cbi], x0 = sx0[cbi];
                        float y1 = sy1[cbi], x1 = sx1[cbi];
                        wtup[0] = y0; wtup[1] = x0; wtup[2] = y1; wtup[3] = x1;
                        orow[it*6+0] = y0; orow[it*6+1] = x0;
                        orow[it*6+2] = y1; orow[it*6+3] = x1;
                        orow[it*6+4] = cbs; orow[it*6+5] = scl[cbi];
                    } else {
                        orow[it*6+0] = 0.f; orow[it*6+1] = 0.f; orow[it*6+2] = 0.f;
                        orow[it*6+3] = 0.f; orow[it*6+4] = 0.f; orow[it*6+5] = 0.f;
                    }
                }
            }
            __syncthreads();                        // B: winner published

            int wi = wbi;
            if (wi >= 0) {
                float wy0 = wtup[0], wx0 = wtup[1];
                float wy1 = wtup[2], wx1 = wtup[3];
                float a1 = fmaxf(wy1 - wy0, 0.f) * fmaxf(wx1 - wx0, 0.f);
#pragma unroll
                for (int k = 0; k < KR; ++k) {      // pure register math
                    int j = tid + (k << 9);
                    if (j == wi) rs[k] = NEGV;      // reference kills selected
                    float ty = fmaxf(wy0, rb[k].x);
                    float tx = fmaxf(wx0, rb[k].y);
                    float by = fminf(wy1, rb[k].z);
                    float bx = fminf(wx1, rb[k].w);
                    float inter = fmaxf(by - ty, 0.f) * fmaxf(bx - tx, 0.f);
                    float a2 = fmaxf(rb[k].z - rb[k].x, 0.f)
                             * fmaxf(rb[k].w - rb[k].y, 0.f);
                    float iou = inter / (a1 + a2 - inter + 1e-9f);
                    if (iou > IOU_T) rs[k] = NEGV;
                }
            }
            // no third barrier needed: psc/pix reads (wave 0) all happened
            // before barrier B; next iteration's writes happen after it.
        }
    } else {
        // -------- fallback: idempotent via pscratch (never hit: M ~1500) ---
        for (int j = tid; j < M; j += NMS_THREADS) pscratch[j] = pscore[j];
        __syncthreads();

        for (int it = 0; it < MAXOUT; ++it) {
            float bs = -INFINITY; int bi = -1;
            for (int j = tid; j < M; j += NMS_THREADS) {
                float v = pscratch[j];
                if (v > bs) { bs = v; bi = j; }
            }
#pragma unroll
            for (int off = 32; off; off >>= 1) {
                float os = __shfl_xor(bs, off);
                int   oi = __shfl_xor(bi, off);
                if (os > bs || (os == bs && oi != -1 && (bi == -1 || oi < bi))) {
                    bs = os; bi = oi;
                }
            }
            if (lane == 0) { psc[wid] = bs; pix[wid] = bi; }
            __syncthreads();
            bs = psc[0]; bi = pix[0];
#pragma unroll
            for (int w = 1; w < NWAVES; ++w) {
                float os = psc[w]; int oi = pix[w];
                if (os > bs || (os == bs && oi != -1 && (bi == -1 || oi < bi))) {
                    bs = os; bi = oi;
                }
            }
            bool valid = (bi >= 0) && (bs > NEGV * 0.5f);
            float4 wb = make_float4(0.f, 0.f, 0.f, 0.f);
            if (valid) wb = pbox[bi];
            if (tid == 0) {
                if (valid) {
                    orow[it*6+0] = wb.x; orow[it*6+1] = wb.y;
                    orow[it*6+2] = wb.z; orow[it*6+3] = wb.w;
                    orow[it*6+4] = bs;   orow[it*6+5] = pcls[bi];
                    pscratch[bi] = NEGV;
                } else {
                    orow[it*6+0] = 0.f; orow[it*6+1] = 0.f; orow[it*6+2] = 0.f;
                    orow[it*6+3] = 0.f; orow[it*6+4] = 0.f; orow[it*6+5] = 0.f;
                }
            }
            __syncthreads();
            if (valid) {
                float a1 = fmaxf(wb.z - wb.x, 0.f) * fmaxf(wb.w - wb.y, 0.f);
                for (int j = tid; j < M; j += NMS_THREADS) {
                    float4 bj = pbox[j];
                    float ty = fmaxf(wb.x, bj.x);
                    float tx = fmaxf(wb.y, bj.y);
                    float by = fminf(wb.z, bj.z);
                    float bx = fminf(wb.w, bj.w);
                    float inter = fmaxf(by - ty, 0.f) * fmaxf(bx - tx, 0.f);
                    float a2 = fmaxf(bj.z - bj.x, 0.f) * fmaxf(bj.w - bj.y, 0.f);
                    float iou = inter / (a1 + a2 - inter + 1e-9f);
                    if (iou > IOU_T) pscratch[j] = NEGV;
                }
            }
            __syncthreads();
        }
    }

    __syncthreads();
    if (tid < MAXOUT * 6) out[tid] = orow[tid];   // single coalesced write
}

extern "C" void kernel_launch(void* const* d_in, const int* in_sizes, int n_in,
                              void* d_out, int out_size, void* d_ws, size_t ws_size,
                              hipStream_t stream) {
    (void)n_in; (void)out_size;
    const float* preds   = (const float*)d_in[0];
    const float* anchors = (const float*)d_in[1];
    float* out = (float*)d_out;

    int N = in_sizes[0] / CH;   // 216,320 boxes

    // Workspace: [0,64) counter; pbox float4[cap]; pscore, pcls, pscratch.
    char* ws = (char*)d_ws;
    int* counter = (int*)ws;
    size_t avail = (ws_size > 64) ? (ws_size - 64) : 0;
    long long cap = (long long)(avail / (sizeof(float4) + 3 * sizeof(float)));
    if (cap > N) cap = N;
    if (cap < 0) cap = 0;
    int capacity = (int)cap;

    float4* pbox    = (float4*)(ws + 64);
    float* pscore   = (float*)(pbox + capacity);
    float* pcls     = pscore + capacity;
    float* pscratch = pcls + capacity;

    init_counter_kernel<<<1, 1, 0, stream>>>(counter);

    int nBlocks = (N + WAVES_PB * BPW - 1) / (WAVES_PB * BPW);   // 1690
    decode_kernel<<<nBlocks, 256, 0, stream>>>(
        preds, anchors, pbox, pscore, pcls, counter, N, capacity);
    nms_kernel<<<1, NMS_THREADS, 0, stream>>>(
        pbox, pscore, pcls, counter, capacity, pscratch, out);
}